// Round 9
// baseline (548.981 us; speedup 1.0000x reference)
//
#include <hip/hip_runtime.h>
#include <hip/hip_bf16.h>

using bf16 = __hip_bfloat16;
typedef __attribute__((ext_vector_type(8))) short short8;   // 8 x bf16 (4 VGPRs)
typedef __attribute__((ext_vector_type(4))) float f32x4;

#define B_   16
#define C_   512
#define N_   4096
#define NG   8
#define GRP_ELEMS (64 * 4096)
static constexpr float kScale = 0.04419417382415922f;  // 512^-0.5
#define SPART_STRIDE 4194304ULL  // 16*512*512 f32 elements per split-K partial

// ---------------- memory layout ----------------
// d_ws: WQ 1.5MB | WP 0.5MB | STATS | Q 64MB | K 64MB | VT 64MB
//   attn (8MB) aliases Q (dead after QK^T); O_t (64MB) aliases K.
// d_out doubles as scratch: xn_t bf16 64MB (dead after QKV), then S partials
//   f32 4x16MB. Final proj kernel rewrites all of d_out.
#define OFF_WQ    0ULL
#define OFF_WP    0x180000ULL
#define OFF_STATS 0x200000ULL
#define OFF_Q     0x400000ULL
#define OFF_K     (OFF_Q  + 0x4000000ULL)
#define OFF_VT    (OFF_K  + 0x4000000ULL)
#define OFF_ATT   OFF_Q
#define OFF_OT    OFF_K

typedef __attribute__((address_space(1))) const void* as1cvp;
typedef __attribute__((address_space(3))) void* as3vp;

__device__ inline void gload_lds16(const void* g, void* l) {
  __builtin_amdgcn_global_load_lds((as1cvp)g, (as3vp)l, 16, 0, 0);
}

#define BARX() __builtin_amdgcn_s_barrier()
#define SFEN() __builtin_amdgcn_sched_barrier(0)
#define LG0()  asm volatile("s_waitcnt lgkmcnt(0)" ::: "memory")
#define VM4()  asm volatile("s_waitcnt vmcnt(4)" ::: "memory")
#define VM0()  asm volatile("s_waitcnt vmcnt(0)" ::: "memory")

// ---------------- K0: fp32 weights -> bf16 ----------------
__global__ __launch_bounds__(256) void cvt_weights(const float* __restrict__ wq,
                                                   const float* __restrict__ wp,
                                                   bf16* __restrict__ oq,
                                                   bf16* __restrict__ op) {
  int i = blockIdx.x * 256 + threadIdx.x;
  if (i < 1536 * 512) oq[i] = __float2bfloat16(wq[i]);
  if (i < 512 * 512)  op[i] = __float2bfloat16(wp[i]);
}

// ---------------- K1: GroupNorm stats ----------------
__global__ __launch_bounds__(256) void gn_stats(const float* __restrict__ x,
                                                float* __restrict__ stats) {
  const int bg = blockIdx.x;
  const float4* p = (const float4*)(x + (size_t)bg * GRP_ELEMS);
  float s = 0.f, q = 0.f;
  for (int i = threadIdx.x; i < GRP_ELEMS / 4; i += 256) {
    float4 v = p[i];
    s += v.x + v.y + v.z + v.w;
    q += v.x * v.x + v.y * v.y + v.z * v.z + v.w * v.w;
  }
  for (int off = 32; off; off >>= 1) { s += __shfl_xor(s, off); q += __shfl_xor(q, off); }
  __shared__ float red[8];
  int w = threadIdx.x >> 6;
  if ((threadIdx.x & 63) == 0) { red[w] = s; red[4 + w] = q; }
  __syncthreads();
  if (threadIdx.x == 0) {
    float S = red[0] + red[1] + red[2] + red[3];
    float Q = red[4] + red[5] + red[6] + red[7];
    float mean = S * (1.f / GRP_ELEMS);
    float var  = Q * (1.f / GRP_ELEMS) - mean * mean;
    stats[bg * 2]     = mean;
    stats[bg * 2 + 1] = rsqrtf(var + 1e-5f);
  }
}

// ---------------- K2: normalize + affine + transpose -> xn_t (b,n,c) bf16 ----
__global__ __launch_bounds__(256) void gn_apply_t(const float* __restrict__ x,
                                                  const float* __restrict__ stats,
                                                  const float* __restrict__ nw,
                                                  const float* __restrict__ nb,
                                                  bf16* __restrict__ xnt) {
  const int nt = blockIdx.x;
  const int ct = blockIdx.y;
  const int b  = blockIdx.z;
  __shared__ float tile[64][65];
  const float mean = stats[(b * NG + ct) * 2];
  const float rstd = stats[(b * NG + ct) * 2 + 1];
  const int col = threadIdx.x & 63;
  const int r4  = threadIdx.x >> 6;
#pragma unroll
  for (int p = 0; p < 16; ++p) {
    int cl = p * 4 + r4;
    int c  = ct * 64 + cl;
    float g  = nw[c] * rstd;
    float sh = nb[c] - mean * g;
    float v  = x[((size_t)b * C_ + c) * N_ + nt * 64 + col];
    tile[cl][col] = v * g + sh;
  }
  __syncthreads();
#pragma unroll
  for (int p = 0; p < 16; ++p) {
    int nl = p * 4 + r4;
    xnt[((size_t)b * N_ + nt * 64 + nl) * C_ + ct * 64 + col] =
        __float2bfloat16(tile[col][nl]);
  }
}

// =================================================================
// 8-phase 256x256 NT bf16 GEMM (round-8 schedule, UNCHANGED).
// Round-9 change: all loop-invariant addressing hoisted out of the
// phase loop (HK technique: precomputed swizzled LDS offsets + bases):
//  - offA[4][2] / offB[2][2] LDS read byte-offsets, computed once
//  - 8 LDS buffer base pointers in a const array
//  - stage src offsets srcOff0/1 per thread ((64+r)&7 == r&7, so the
//    swizzle slot is j-invariant); per call only half*128*ld + kt*64
//  - last iteration peeled: steady loop has no `more` branches
// MODE 0: QKV  1536 blk, K=512 (NIT=4)  -> q,k (b,c,n), vt (b,n,c), +bias
// MODE 1: QK^T  256 blk, K=1024 (NIT=8), split-4 over n -> S f32 partial*kScale
// MODE 2: PV    512 blk, K=512 (NIT=4)  -> O_t (b,n,c) bf16
// MODE 3: proj  512 blk, K=512 (NIT=4)  -> out f32 = acc + bias + resid
// =================================================================
template<int MODE>
__global__ __launch_bounds__(512, 2) void gemm8p(
    const bf16* __restrict__ Ag, const bf16* __restrict__ Bg,
    int lda, int ldb, long long sA, long long sB,
    const float* __restrict__ bias,
    void* __restrict__ o0, void* __restrict__ o1, void* __restrict__ o2,
    const float* __restrict__ resid) {
  __shared__ __align__(16) bf16 smem[8][8192];  // [A:0-3 | B:4-7][buf*2+half]

  constexpr int NIT = (MODE == 1) ? 8 : 4;      // 8-phase iterations (2 kt each)
  const int id = blockIdx.x;
  int bx, by, bz, part;
  if constexpr (MODE == 0) {
    const int s = (id & 7) * 192 + (id >> 3);   // 1536 blocks
    by = s % 6;  bx = s / 6;  bz = 0; part = 0;
  } else if constexpr (MODE == 1) {
    const int s = (id & 7) * 32 + (id >> 3);    // 256 blocks
    bx = s & 1; by = (s >> 1) & 1; part = (s >> 2) & 3; bz = s >> 4;
  } else if constexpr (MODE == 2) {
    const int s = (id & 7) * 64 + (id >> 3);    // 512 blocks
    bx = s & 1;  by = (s >> 1) & 15;  bz = s >> 5; part = 0;
  } else {
    const int s = (id & 7) * 64 + (id >> 3);    // 512 blocks
    by = s & 1;  bx = s >> 1;  bz = 0; part = 0;
  }

  const int ld = lda;   // lda == ldb for every call site
  const bf16* Apan = Ag + (size_t)bz * sA + (size_t)by * 256 * lda + (size_t)part * 1024;
  const bf16* Bpan = Bg + (size_t)bz * sB + (size_t)bx * 256 * ldb + (size_t)part * 1024;

  const int tid  = threadIdx.x;
  const int lane = tid & 63;
  const int wid  = tid >> 6;       // 0..7
  const int wr   = wid >> 2;       // 0..1  (M half of wave grid)
  const int wc   = wid & 3;        // 0..3  (N quarter)
  const int mrow = lane & 15, krow = lane >> 4;
  const int wrr  = wr * 64, wcc = wc * 32;

  // ---- hoisted addressing (loop-invariant) ----
  char* const ldsBase[8] = {
    (char*)smem[0], (char*)smem[1], (char*)smem[2], (char*)smem[3],
    (char*)smem[4], (char*)smem[5], (char*)smem[6], (char*)smem[7]};
  int offA[4][2], offB[2][2];
#pragma unroll
  for (int mi = 0; mi < 4; ++mi) {
    const int lr = wrr + mi * 16 + mrow;
#pragma unroll
    for (int s2 = 0; s2 < 2; ++s2)
      offA[mi][s2] = lr * 128 + (((s2 * 4 + krow) ^ (lr & 7)) << 4);
  }
#pragma unroll
  for (int ni = 0; ni < 2; ++ni) {
    const int lr = wcc + ni * 16 + mrow;
#pragma unroll
    for (int s2 = 0; s2 < 2; ++s2)
      offB[ni][s2] = lr * 128 + (((s2 * 4 + krow) ^ (lr & 7)) << 4);
  }
  // stage: r(j=0)=tid>>3, r(j=1)=64+(tid>>3); (64+r)&7==r&7 -> same slot c8
  const int rS     = tid >> 3;
  const int c8S    = (tid & 7) ^ (rS & 7);
  const int srcOff0 = rS * ld + c8S * 8;
  const int srcOff1 = srcOff0 + 64 * ld;
  const int dst0   = tid * 16;
  const int halfStep = 128 * ld;

  // stage one half-tile (2 x gload_lds16/thread)
  auto stage = [&](int mat, int buf, int half, int kt) {
    const bf16* gb = (mat ? Bpan : Apan) + half * halfStep + kt * 64;
    char* dst = ldsBase[mat * 4 + buf * 2 + half];
    gload_lds16(gb + srcOff0, dst + dst0);
    gload_lds16(gb + srcOff1, dst + dst0 + 8192);
  };

  short8 a[4][2], b0[2][2], b1[2][2];
  auto ldA = [&](int buf, int qm) {
    const char* reg = ldsBase[buf * 2 + qm];
#pragma unroll
    for (int mi = 0; mi < 4; ++mi)
#pragma unroll
      for (int s2 = 0; s2 < 2; ++s2)
        a[mi][s2] = *(const short8*)(reg + offA[mi][s2]);
  };
  auto ldB = [&](short8 (&b)[2][2], int buf, int qn) {
    const char* reg = ldsBase[4 + buf * 2 + qn];
#pragma unroll
    for (int ni = 0; ni < 2; ++ni)
#pragma unroll
      for (int s2 = 0; s2 < 2; ++s2)
        b[ni][s2] = *(const short8*)(reg + offB[ni][s2]);
  };

  f32x4 acc[2][2][4][2];
#pragma unroll
  for (int p = 0; p < 2; ++p)
#pragma unroll
    for (int q = 0; q < 2; ++q)
#pragma unroll
      for (int m = 0; m < 4; ++m)
#pragma unroll
        for (int n = 0; n < 2; ++n)
#pragma unroll
          for (int r = 0; r < 4; ++r) acc[p][q][m][n][r] = 0.f;

  auto mm = [&](short8 (&b)[2][2], f32x4 (&c)[4][2]) {
    __builtin_amdgcn_s_setprio(1);
#pragma unroll
    for (int mi = 0; mi < 4; ++mi)
#pragma unroll
      for (int ni = 0; ni < 2; ++ni)
#pragma unroll
        for (int s2 = 0; s2 < 2; ++s2)
          c[mi][ni] = __builtin_amdgcn_mfma_f32_16x16x32_bf16(
              a[mi][s2], b[ni][s2], c[mi][ni], 0, 0, 0);
    __builtin_amdgcn_s_setprio(0);
  };

  // ---- one 8-phase iteration (round-8 schedule, literal `more` folds) ----
  auto iter = [&](int i, bool more) {
    const int kt1 = 2 * i + 1, kt2 = 2 * i + 2, kt3 = 2 * i + 3;
    // ph1: q(0,0) from buf0 | stage (2i+1).Ab
    ldA(0, 0); ldB(b0, 0, 0); stage(0, 1, 1, kt1);
    BARX(); LG0(); SFEN(); mm(b0, acc[0][0]); BARX();
    // ph2: q(0,1) | stage (2i+1).Bb
    ldB(b1, 0, 1); stage(1, 1, 1, kt1);
    BARX(); LG0(); SFEN(); mm(b1, acc[0][1]); BARX();
    // ph3: q(1,0) | stage (2i+2).Aa
    ldA(0, 1); if (more) stage(0, 0, 0, kt2);
    BARX(); LG0(); SFEN(); mm(b0, acc[1][0]); BARX();
    // ph4: q(1,1) | stage (2i+2).Ba | counted wait
    if (more) { stage(1, 0, 0, kt2); VM4(); } else { VM0(); }
    BARX(); SFEN(); mm(b1, acc[1][1]); BARX();
    // ph5: q(0,0) from buf1 | stage (2i+2).Ab
    ldA(1, 0); ldB(b0, 1, 0); if (more) stage(0, 0, 1, kt2);
    BARX(); LG0(); SFEN(); mm(b0, acc[0][0]); BARX();
    // ph6: q(0,1) | stage (2i+2).Bb
    ldB(b1, 1, 1); if (more) stage(1, 0, 1, kt2);
    BARX(); LG0(); SFEN(); mm(b1, acc[0][1]); BARX();
    // ph7: q(1,0) | stage (2i+3).Aa
    ldA(1, 1); if (more) stage(0, 1, 0, kt3);
    BARX(); LG0(); SFEN(); mm(b0, acc[1][0]); BARX();
    // ph8: q(1,1) | stage (2i+3).Ba | counted wait
    if (more) { stage(1, 1, 0, kt3); VM4(); }
    BARX(); SFEN(); mm(b1, acc[1][1]);
    if (more) BARX();
  };

  // ---- prologue: K-tile0 all 4 halves, K-tile1 Aa+Ba ----
  stage(0, 0, 0, 0); stage(0, 0, 1, 0); stage(1, 0, 0, 0); stage(1, 0, 1, 0);
  stage(0, 1, 0, 1); stage(1, 1, 0, 1);
  VM4(); BARX(); SFEN();

  // ---- main loop: steady iterations branch-free, last peeled ----
  for (int i = 0; i < NIT - 1; ++i) iter(i, true);
  iter(NIT - 1, false);

  // ---- epilogue ----
#pragma unroll
  for (int qm = 0; qm < 2; ++qm)
#pragma unroll
  for (int qn = 0; qn < 2; ++qn)
#pragma unroll
  for (int mi = 0; mi < 4; ++mi)
#pragma unroll
  for (int ni = 0; ni < 2; ++ni)
#pragma unroll
  for (int rr = 0; rr < 4; ++rr) {
    const int row_l = qm * 128 + wrr + mi * 16 + krow * 4 + rr;
    const int col_l = qn * 128 + wcc + ni * 16 + mrow;
    float v = acc[qm][qn][mi][ni][rr];
    if constexpr (MODE == 0) {
      const int o = by * 256 + row_l;            // 0..1536
      v += bias[o];
      const int j = bx * 256 + col_l;            // 0..65536
      const int bidx = j >> 12, n = j & 4095;
      const int which = o >> 9, ol = o & 511;
      if (which == 0)
        ((bf16*)o0)[((size_t)bidx * C_ + ol) * N_ + n] = __float2bfloat16(v);
      else if (which == 1)
        ((bf16*)o1)[((size_t)bidx * C_ + ol) * N_ + n] = __float2bfloat16(v);
      else
        ((bf16*)o2)[((size_t)bidx * N_ + n) * C_ + ol] = __float2bfloat16(v);
    } else if constexpr (MODE == 1) {
      const int row = by * 256 + row_l, colg = bx * 256 + col_l;
      ((float*)o0)[(size_t)part * SPART_STRIDE + (size_t)bz * 262144 +
                   row * 512 + colg] = v * kScale;
    } else if constexpr (MODE == 2) {
      const int row = by * 256 + row_l, colg = bx * 256 + col_l;
      ((bf16*)o0)[((size_t)bz * N_ + row) * C_ + colg] = __float2bfloat16(v);
    } else {
      const int o = by * 256 + row_l;
      const int j = bx * 256 + col_l;
      const int bidx = j >> 12, n = j & 4095;
      const size_t addr = ((size_t)bidx * C_ + o) * N_ + n;
      ((float*)o0)[addr] = v + bias[o] + resid[addr];
    }
  }
}

// ---------------- K5: row softmax over 4 split-K partials -> attn bf16 ------
__global__ __launch_bounds__(256) void softmax_rows(const float* __restrict__ S,
                                                    bf16* __restrict__ att) {
  const int row  = blockIdx.x * 4 + (threadIdx.x >> 6);
  const int lane = threadIdx.x & 63;
  const float* p = S + (size_t)row * 512;
  float v[8];
  float mx = -1e30f;
#pragma unroll
  for (int i = 0; i < 8; ++i) {
    int idx = lane + i * 64;
    v[i] = p[idx] + p[SPART_STRIDE + idx] + p[2 * SPART_STRIDE + idx] +
           p[3 * SPART_STRIDE + idx];
    mx = fmaxf(mx, v[i]);
  }
  for (int off = 32; off; off >>= 1) mx = fmaxf(mx, __shfl_xor(mx, off));
  float s = 0.f;
#pragma unroll
  for (int i = 0; i < 8; ++i) { v[i] = __expf(v[i] - mx); s += v[i]; }
  for (int off = 32; off; off >>= 1) s += __shfl_xor(s, off);
  float inv = 1.f / s;
  bf16* q = att + (size_t)row * 512;
#pragma unroll
  for (int i = 0; i < 8; ++i) q[lane + i * 64] = __float2bfloat16(v[i] * inv);
}

extern "C" void kernel_launch(void* const* d_in, const int* in_sizes, int n_in,
                              void* d_out, int out_size, void* d_ws, size_t ws_size,
                              hipStream_t stream) {
  const float* x      = (const float*)d_in[0];
  const float* norm_w = (const float*)d_in[1];
  const float* norm_b = (const float*)d_in[2];
  const float* qkv_w  = (const float*)d_in[3];
  const float* qkv_b  = (const float*)d_in[4];
  const float* proj_w = (const float*)d_in[5];
  const float* proj_b = (const float*)d_in[6];
  float* out = (float*)d_out;
  char* ws = (char*)d_ws;

  bf16*  wq    = (bf16*)(ws + OFF_WQ);
  bf16*  wp    = (bf16*)(ws + OFF_WP);
  float* stats = (float*)(ws + OFF_STATS);
  bf16*  q     = (bf16*)(ws + OFF_Q);
  bf16*  k     = (bf16*)(ws + OFF_K);
  bf16*  vt    = (bf16*)(ws + OFF_VT);
  bf16*  att   = (bf16*)(ws + OFF_ATT);   // aliases Q (dead after QK^T)
  bf16*  ot    = (bf16*)(ws + OFF_OT);    // aliases K (dead after QK^T)
  bf16*  xnt   = (bf16*)d_out;            // 64 MB, dead after QKV GEMM
  float* S     = (float*)d_out;           // 4 x 16 MB partials, after xnt dead

  cvt_weights<<<3072, 256, 0, stream>>>(qkv_w, proj_w, wq, wp);
  gn_stats<<<128, 256, 0, stream>>>(x, stats);
  gn_apply_t<<<dim3(64, 8, 16), 256, 0, stream>>>(x, stats, norm_w, norm_b, xnt);
  // QKV: M=1536, N=65536, K=512; 6x256 tiles -> 1536 blocks
  gemm8p<0><<<1536, 512, 0, stream>>>(wq, xnt, 512, 512, 0, 0, qkv_b,
                                      q, k, vt, nullptr);
  // QK^T: per (batch, part) 2x2 tiles of 256^2, K=1024/block -> 256 blocks
  gemm8p<1><<<256, 512, 0, stream>>>(q, k, 4096, 4096, 512LL * 4096,
                                     512LL * 4096, nullptr, S, nullptr,
                                     nullptr, nullptr);
  softmax_rows<<<2048, 256, 0, stream>>>(S, att);
  // PV per batch: M=4096 (n), N=512 (c), K=512 (d); A=v_t, B=attn
  gemm8p<2><<<512, 512, 0, stream>>>(vt, att, 512, 512, 4096LL * 512,
                                     512LL * 512, nullptr, ot, nullptr,
                                     nullptr, nullptr);
  // proj: M=512, N=65536, K=512; + bias + residual
  gemm8p<3><<<512, 512, 0, stream>>>(wp, ot, 512, 512, 0, 0, proj_b,
                                     out, nullptr, nullptr, x);
}

// Round 10
// 524.697 us; speedup vs baseline: 1.0463x; 1.0463x over previous
//
#include <hip/hip_runtime.h>
#include <hip/hip_bf16.h>

using bf16 = __hip_bfloat16;
typedef __attribute__((ext_vector_type(8))) short short8;   // 8 x bf16 (4 VGPRs)
typedef __attribute__((ext_vector_type(4))) float f32x4;
typedef __attribute__((ext_vector_type(4))) short short4v;

#define B_   16
#define C_   512
#define N_   4096
#define NG   8
#define GRP_ELEMS (64 * 4096)
static constexpr float kScale = 0.04419417382415922f;  // 512^-0.5
#define SPART_STRIDE 4194304ULL  // 16*512*512 f32 elements per split-K partial

// ---------------- memory layout ----------------
// d_ws: WQ 1.5MB | WP 0.5MB | STATS | Q 64MB | K 64MB | VT 64MB
//   att_t (8MB) aliases Q (q dead after QK^T); W2 (8MB) aliases K (dead after QK^T).
// d_out doubles as scratch: xn_t bf16 64MB (dead after QKV), then S partials
//   f32 4x16MB. Final GEMM rewrites all of d_out.
#define OFF_WQ    0ULL
#define OFF_WP    0x180000ULL
#define OFF_STATS 0x200000ULL
#define OFF_Q     0x400000ULL
#define OFF_K     (OFF_Q  + 0x4000000ULL)
#define OFF_VT    (OFF_K  + 0x4000000ULL)
#define OFF_ATT   OFF_Q
#define OFF_W2    OFF_K

typedef __attribute__((address_space(1))) const void* as1cvp;
typedef __attribute__((address_space(3))) void* as3vp;

__device__ inline void gload_lds16(const void* g, void* l) {
  __builtin_amdgcn_global_load_lds((as1cvp)g, (as3vp)l, 16, 0, 0);
}

#define BARX() __builtin_amdgcn_s_barrier()
#define SFEN() __builtin_amdgcn_sched_barrier(0)
#define LG0()  asm volatile("s_waitcnt lgkmcnt(0)" ::: "memory")
#define VM4()  asm volatile("s_waitcnt vmcnt(4)" ::: "memory")
#define VM0()  asm volatile("s_waitcnt vmcnt(0)" ::: "memory")

// ---------------- K0: fp32 weights -> bf16 ----------------
__global__ __launch_bounds__(256) void cvt_weights(const float* __restrict__ wq,
                                                   const float* __restrict__ wp,
                                                   bf16* __restrict__ oq,
                                                   bf16* __restrict__ op) {
  int i = blockIdx.x * 256 + threadIdx.x;
  if (i < 1536 * 512) oq[i] = __float2bfloat16(wq[i]);
  if (i < 512 * 512)  op[i] = __float2bfloat16(wp[i]);
}

// ---------------- K1: GroupNorm stats ----------------
__global__ __launch_bounds__(256) void gn_stats(const float* __restrict__ x,
                                                float* __restrict__ stats) {
  const int bg = blockIdx.x;
  const float4* p = (const float4*)(x + (size_t)bg * GRP_ELEMS);
  float s = 0.f, q = 0.f;
  for (int i = threadIdx.x; i < GRP_ELEMS / 4; i += 256) {
    float4 v = p[i];
    s += v.x + v.y + v.z + v.w;
    q += v.x * v.x + v.y * v.y + v.z * v.z + v.w * v.w;
  }
  for (int off = 32; off; off >>= 1) { s += __shfl_xor(s, off); q += __shfl_xor(q, off); }
  __shared__ float red[8];
  int w = threadIdx.x >> 6;
  if ((threadIdx.x & 63) == 0) { red[w] = s; red[4 + w] = q; }
  __syncthreads();
  if (threadIdx.x == 0) {
    float S = red[0] + red[1] + red[2] + red[3];
    float Q = red[4] + red[5] + red[6] + red[7];
    float mean = S * (1.f / GRP_ELEMS);
    float var  = Q * (1.f / GRP_ELEMS) - mean * mean;
    stats[bg * 2]     = mean;
    stats[bg * 2 + 1] = rsqrtf(var + 1e-5f);
  }
}

// ---------------- K2: normalize + affine + transpose -> xn_t (b,n,c) bf16 ----
__global__ __launch_bounds__(256) void gn_apply_t(const float* __restrict__ x,
                                                  const float* __restrict__ stats,
                                                  const float* __restrict__ nw,
                                                  const float* __restrict__ nb,
                                                  bf16* __restrict__ xnt) {
  const int nt = blockIdx.x;
  const int ct = blockIdx.y;
  const int b  = blockIdx.z;
  __shared__ float tile[64][65];
  const float mean = stats[(b * NG + ct) * 2];
  const float rstd = stats[(b * NG + ct) * 2 + 1];
  const int col = threadIdx.x & 63;
  const int r4  = threadIdx.x >> 6;
#pragma unroll
  for (int p = 0; p < 16; ++p) {
    int cl = p * 4 + r4;
    int c  = ct * 64 + cl;
    float g  = nw[c] * rstd;
    float sh = nb[c] - mean * g;
    float v  = x[((size_t)b * C_ + c) * N_ + nt * 64 + col];
    tile[cl][col] = v * g + sh;
  }
  __syncthreads();
#pragma unroll
  for (int p = 0; p < 16; ++p) {
    int nl = p * 4 + r4;
    xnt[((size_t)b * N_ + nt * 64 + nl) * C_ + ct * 64 + col] =
        __float2bfloat16(tile[col][nl]);
  }
}

// =================================================================
// 8-phase 256x256 NT bf16 GEMM (round-8 verified schedule, core
// unchanged).  BK=64, 8 waves (2Mx4N), 512 thr, LDS 128 KiB.
// MODE 0: QKV  1536 blk, K=512 (NIT=4)  -> q,k (b,c,n), vt (b,n,c), +bias
// MODE 1: QK^T  256 blk, K=1024 (NIT=8), split-4 over n -> S f32 partial*kScale
// MODE 2: W2     64 blk, K=512 (NIT=4), per batch: W2[b]=wp*att_t^T (bf16)
// MODE 3: final 512 blk, K=512 (NIT=4), per batch: out=W2*vt^T +bias+resid
// =================================================================
template<int MODE>
__global__ __launch_bounds__(512, 2) void gemm8p(
    const bf16* __restrict__ Ag, const bf16* __restrict__ Bg,
    int lda, int ldb, long long sA, long long sB,
    const float* __restrict__ bias,
    void* __restrict__ o0, void* __restrict__ o1, void* __restrict__ o2,
    const float* __restrict__ resid) {
  __shared__ __align__(16) bf16 smem[8][8192];  // [A:0-3 | B:4-7][buf*2+half]

  constexpr int NIT = (MODE == 1) ? 8 : 4;      // 8-phase iterations (2 kt each)
  const int id = blockIdx.x;
  int bx, by, bz, part;
  if constexpr (MODE == 0) {
    const int s = (id & 7) * 192 + (id >> 3);   // 1536 blocks
    by = s % 6;  bx = s / 6;  bz = 0; part = 0;
  } else if constexpr (MODE == 1) {
    const int s = (id & 7) * 32 + (id >> 3);    // 256 blocks
    bx = s & 1; by = (s >> 1) & 1; part = (s >> 2) & 3; bz = s >> 4;
  } else if constexpr (MODE == 2) {
    const int s = (id & 7) * 8 + (id >> 3);     // 64 blocks
    bx = s & 1;  by = (s >> 1) & 1;  bz = s >> 2; part = 0;
  } else {
    const int s = (id & 7) * 64 + (id >> 3);    // 512 blocks
    by = s & 1;  bx = (s >> 1) & 15;  bz = s >> 5; part = 0;
  }

  const bf16* Apan = Ag + (size_t)bz * sA + (size_t)by * 256 * lda + (size_t)part * 1024;
  const bf16* Bpan = Bg + (size_t)bz * sB + (size_t)bx * 256 * ldb + (size_t)part * 1024;

  const int tid  = threadIdx.x;
  const int lane = tid & 63;
  const int wid  = tid >> 6;       // 0..7
  const int wr   = wid >> 2;       // 0..1  (M half of wave grid)
  const int wc   = wid & 3;        // 0..3  (N quarter)
  const int mrow = lane & 15, krow = lane >> 4;
  const int wrr  = wr * 64, wcc = wc * 32;

  // stage one half-tile (2 x gload_lds16/thread); inverse-swizzled source
  auto stage = [&](int mat, int buf, int half, int kt) {
    const bf16* gb = mat ? Bpan : Apan;
    const int ld = mat ? ldb : lda;
    char* reg = (char*)smem[mat * 4 + buf * 2 + half];
#pragma unroll
    for (int j = 0; j < 2; ++j) {
      const int idx = j * 512 + tid;
      const int r   = idx >> 3;                  // 0..127 local row
      const int c8  = (tid & 7) ^ (r & 7);       // inverse swizzle of 16B slot
      gload_lds16(gb + (size_t)(half * 128 + r) * ld + kt * 64 + c8 * 8,
                  reg + idx * 16);
    }
  };

  short8 a[4][2], b0[2][2], b1[2][2];
  auto ldA = [&](int buf, int qm) {
    const char* reg = (const char*)smem[buf * 2 + qm];
#pragma unroll
    for (int mi = 0; mi < 4; ++mi) {
      const int lr = wrr + mi * 16 + mrow;
#pragma unroll
      for (int s2 = 0; s2 < 2; ++s2)
        a[mi][s2] = *(const short8*)(reg + lr * 128 +
                                     (((s2 * 4 + krow) ^ (lr & 7)) << 4));
    }
  };
  auto ldB = [&](short8 (&b)[2][2], int buf, int qn) {
    const char* reg = (const char*)smem[4 + buf * 2 + qn];
#pragma unroll
    for (int ni = 0; ni < 2; ++ni) {
      const int lr = wcc + ni * 16 + mrow;
#pragma unroll
      for (int s2 = 0; s2 < 2; ++s2)
        b[ni][s2] = *(const short8*)(reg + lr * 128 +
                                     (((s2 * 4 + krow) ^ (lr & 7)) << 4));
    }
  };

  f32x4 acc[2][2][4][2];
#pragma unroll
  for (int p = 0; p < 2; ++p)
#pragma unroll
    for (int q = 0; q < 2; ++q)
#pragma unroll
      for (int m = 0; m < 4; ++m)
#pragma unroll
        for (int n = 0; n < 2; ++n)
#pragma unroll
          for (int r = 0; r < 4; ++r) acc[p][q][m][n][r] = 0.f;

  auto mm = [&](short8 (&b)[2][2], f32x4 (&c)[4][2]) {
    __builtin_amdgcn_s_setprio(1);
#pragma unroll
    for (int mi = 0; mi < 4; ++mi)
#pragma unroll
      for (int ni = 0; ni < 2; ++ni)
#pragma unroll
        for (int s2 = 0; s2 < 2; ++s2)
          c[mi][ni] = __builtin_amdgcn_mfma_f32_16x16x32_bf16(
              a[mi][s2], b[ni][s2], c[mi][ni], 0, 0, 0);
    __builtin_amdgcn_s_setprio(0);
  };

  // ---- prologue: K-tile0 all 4 halves, K-tile1 Aa+Ba ----
  stage(0, 0, 0, 0); stage(0, 0, 1, 0); stage(1, 0, 0, 0); stage(1, 0, 1, 0);
  stage(0, 1, 0, 1); stage(1, 1, 0, 1);
  VM4(); BARX(); SFEN();

  // ---- main loop: iter i computes K-tiles 2i (buf0), 2i+1 (buf1) ----
  for (int i = 0; i < NIT; ++i) {
    const int kt1 = 2 * i + 1, kt2 = 2 * i + 2, kt3 = 2 * i + 3;
    const bool more = (i < NIT - 1);
    // ph1: q(0,0) from buf0 | stage (2i+1).Ab
    ldA(0, 0); ldB(b0, 0, 0); stage(0, 1, 1, kt1);
    BARX(); LG0(); SFEN(); mm(b0, acc[0][0]); BARX();
    // ph2: q(0,1) | stage (2i+1).Bb
    ldB(b1, 0, 1); stage(1, 1, 1, kt1);
    BARX(); LG0(); SFEN(); mm(b1, acc[0][1]); BARX();
    // ph3: q(1,0) | stage (2i+2).Aa
    ldA(0, 1); if (more) stage(0, 0, 0, kt2);
    BARX(); LG0(); SFEN(); mm(b0, acc[1][0]); BARX();
    // ph4: q(1,1) | stage (2i+2).Ba | counted wait
    if (more) { stage(1, 0, 0, kt2); VM4(); } else { VM0(); }
    BARX(); SFEN(); mm(b1, acc[1][1]); BARX();
    // ph5: q(0,0) from buf1 | stage (2i+2).Ab
    ldA(1, 0); ldB(b0, 1, 0); if (more) stage(0, 0, 1, kt2);
    BARX(); LG0(); SFEN(); mm(b0, acc[0][0]); BARX();
    // ph6: q(0,1) | stage (2i+2).Bb
    ldB(b1, 1, 1); if (more) stage(1, 0, 1, kt2);
    BARX(); LG0(); SFEN(); mm(b1, acc[0][1]); BARX();
    // ph7: q(1,0) | stage (2i+3).Aa
    ldA(1, 1); if (more) stage(0, 1, 0, kt3);
    BARX(); LG0(); SFEN(); mm(b0, acc[1][0]); BARX();
    // ph8: q(1,1) | stage (2i+3).Ba | counted wait
    if (more) { stage(1, 1, 0, kt3); VM4(); }
    BARX(); SFEN(); mm(b1, acc[1][1]);
    if (more) BARX();
  }

  // ---- epilogue ----
#pragma unroll
  for (int qm = 0; qm < 2; ++qm)
#pragma unroll
  for (int qn = 0; qn < 2; ++qn)
#pragma unroll
  for (int mi = 0; mi < 4; ++mi)
#pragma unroll
  for (int ni = 0; ni < 2; ++ni)
#pragma unroll
  for (int rr = 0; rr < 4; ++rr) {
    const int row_l = qm * 128 + wrr + mi * 16 + krow * 4 + rr;
    const int col_l = qn * 128 + wcc + ni * 16 + mrow;
    float v = acc[qm][qn][mi][ni][rr];
    if constexpr (MODE == 0) {
      const int o = by * 256 + row_l;            // 0..1536
      v += bias[o];
      const int j = bx * 256 + col_l;            // 0..65536
      const int bidx = j >> 12, n = j & 4095;
      const int which = o >> 9, ol = o & 511;
      if (which == 0)
        ((bf16*)o0)[((size_t)bidx * C_ + ol) * N_ + n] = __float2bfloat16(v);
      else if (which == 1)
        ((bf16*)o1)[((size_t)bidx * C_ + ol) * N_ + n] = __float2bfloat16(v);
      else
        ((bf16*)o2)[((size_t)bidx * N_ + n) * C_ + ol] = __float2bfloat16(v);
    } else if constexpr (MODE == 1) {
      const int row = by * 256 + row_l, colg = bx * 256 + col_l;
      ((float*)o0)[(size_t)part * SPART_STRIDE + (size_t)bz * 262144 +
                   row * 512 + colg] = v * kScale;
    } else if constexpr (MODE == 2) {
      // W2[b][o][d] = sum_c wp[o][c] * att_t[d][c]
      const int o = by * 256 + row_l, d = bx * 256 + col_l;
      ((bf16*)o0)[(size_t)bz * 262144 + o * 512 + d] = __float2bfloat16(v);
    } else {
      // out[b][o][n] = sum_d W2[b][o][d] * vt[n][d] + bias[o] + resid
      const int o = by * 256 + row_l;
      const int n = bx * 256 + col_l;
      const size_t addr = ((size_t)bz * C_ + o) * N_ + n;
      ((float*)o0)[addr] = v + bias[o] + resid[addr];
    }
  }
}

// ---------------- K5: softmax over 4 split-K partials -> att_t (b,d,c) ------
// Block = (batch b, 64-row c-tile). Row softmax as before, staged transposed
// in LDS, written out coalesced as att_t[b][d][c0..c0+64).
__global__ __launch_bounds__(256) void softmax_t(const float* __restrict__ S,
                                                 bf16* __restrict__ att_t) {
  const int b  = blockIdx.x >> 3;
  const int ct = blockIdx.x & 7;
  __shared__ bf16 T[512][68];   // [d][c_local], pad->136B row stride (8B-aligned)
  const int w = threadIdx.x >> 6, lane = threadIdx.x & 63;
  for (int it = 0; it < 16; ++it) {
    const int cl  = w * 16 + it;                  // local c 0..63
    const int row = b * 512 + ct * 64 + cl;       // global S row (c)
    const float* p = S + (size_t)row * 512;
    float v[8];
    float mx = -1e30f;
#pragma unroll
    for (int i = 0; i < 8; ++i) {
      int idx = lane + i * 64;
      v[i] = p[idx] + p[SPART_STRIDE + idx] + p[2 * SPART_STRIDE + idx] +
             p[3 * SPART_STRIDE + idx];
      mx = fmaxf(mx, v[i]);
    }
    for (int off = 32; off; off >>= 1) mx = fmaxf(mx, __shfl_xor(mx, off));
    float s = 0.f;
#pragma unroll
    for (int i = 0; i < 8; ++i) { v[i] = __expf(v[i] - mx); s += v[i]; }
    for (int off = 32; off; off >>= 1) s += __shfl_xor(s, off);
    float inv = 1.f / s;
#pragma unroll
    for (int i = 0; i < 8; ++i) T[lane + i * 64][cl] = __float2bfloat16(v[i] * inv);
  }
  __syncthreads();
  // coalesced transposed write: thread -> (d = it*16 + tid>>4, 4 c's)
  bf16* outp = att_t + (size_t)b * 262144 + ct * 64;
  const int dof = threadIdx.x >> 4;
  const int c4  = (threadIdx.x & 15) * 4;
  for (int it = 0; it < 32; ++it) {
    const int d = it * 16 + dof;
    *(short4v*)(outp + (size_t)d * 512 + c4) = *(const short4v*)(&T[d][c4]);
  }
}

extern "C" void kernel_launch(void* const* d_in, const int* in_sizes, int n_in,
                              void* d_out, int out_size, void* d_ws, size_t ws_size,
                              hipStream_t stream) {
  const float* x      = (const float*)d_in[0];
  const float* norm_w = (const float*)d_in[1];
  const float* norm_b = (const float*)d_in[2];
  const float* qkv_w  = (const float*)d_in[3];
  const float* qkv_b  = (const float*)d_in[4];
  const float* proj_w = (const float*)d_in[5];
  const float* proj_b = (const float*)d_in[6];
  float* out = (float*)d_out;
  char* ws = (char*)d_ws;

  bf16*  wq    = (bf16*)(ws + OFF_WQ);
  bf16*  wp    = (bf16*)(ws + OFF_WP);
  float* stats = (float*)(ws + OFF_STATS);
  bf16*  q     = (bf16*)(ws + OFF_Q);
  bf16*  k     = (bf16*)(ws + OFF_K);
  bf16*  vt    = (bf16*)(ws + OFF_VT);
  bf16*  att_t = (bf16*)(ws + OFF_ATT);   // aliases Q (q dead after QK^T)
  bf16*  w2    = (bf16*)(ws + OFF_W2);    // aliases K (k dead after QK^T)
  bf16*  xnt   = (bf16*)d_out;            // 64 MB, dead after QKV GEMM
  float* S     = (float*)d_out;           // 4 x 16 MB partials, after xnt dead

  cvt_weights<<<3072, 256, 0, stream>>>(qkv_w, proj_w, wq, wp);
  gn_stats<<<128, 256, 0, stream>>>(x, stats);
  gn_apply_t<<<dim3(64, 8, 16), 256, 0, stream>>>(x, stats, norm_w, norm_b, xnt);
  // QKV: M=1536, N=65536, K=512; 6x256 tiles -> 1536 blocks
  gemm8p<0><<<1536, 512, 0, stream>>>(wq, xnt, 512, 512, 0, 0, qkv_b,
                                      q, k, vt, nullptr);
  // QK^T: per (batch, part) 2x2 tiles of 256^2, K=1024/block -> 256 blocks
  gemm8p<1><<<256, 512, 0, stream>>>(q, k, 4096, 4096, 512LL * 4096,
                                     512LL * 4096, nullptr, S, nullptr,
                                     nullptr, nullptr);
  // softmax + transpose: 16 batches x 8 c-tiles -> att_t (b,d,c) bf16
  softmax_t<<<128, 256, 0, stream>>>(S, att_t);
  // W2 = wp * att^T: per batch M=512(o), N=512(d), K=512(c); 64 blocks
  gemm8p<2><<<64, 512, 0, stream>>>(wp, att_t, 512, 512, 0, 262144LL,
                                    nullptr, w2, nullptr, nullptr, nullptr);
  // out = W2 * v: per batch M=512(o), N=4096(n), K=512(d); +bias+resid
  gemm8p<3><<<512, 512, 0, stream>>>(w2, vt, 512, 512, 262144LL, 4096LL * 512,
                                     proj_b, out, nullptr, nullptr, x);
}